// Round 10
// baseline (1767.464 us; speedup 1.0000x reference)
//
#include <hip/hip_runtime.h>
#include <hip/hip_bf16.h>
#include <math.h>

// Problem constants
#define VV 50257
#define DD 1024
#define LL 6
#define HH 16
#define BB 4
#define TT 1024
#define HD 64
#define BT (BB*TT)          // 4096 rows

typedef __attribute__((ext_vector_type(8))) short bf16x8;
typedef __attribute__((ext_vector_type(8))) _Float16 f16x8;
typedef __attribute__((ext_vector_type(4))) float f32x4;
typedef __attribute__((ext_vector_type(16))) float f32x16;

__device__ inline float b2f(unsigned short u) {
    unsigned x = ((unsigned)u) << 16;
    return __uint_as_float(x);
}
__device__ inline unsigned short f2b(float f) {
    __hip_bfloat16 h = __float2bfloat16(f);   // RNE
    return *reinterpret_cast<unsigned short*>(&h);
}
__device__ inline void plswap32(unsigned &dst, unsigned &src) {
    // v_permlane32_swap_b32: for i in 0..31: swap(dst[i+32], src[i])
    asm("v_permlane32_swap_b32 %0, %1" : "+v"(dst), "+v"(src));
}

#define GLOAD16(g, l) __builtin_amdgcn_global_load_lds( \
    (const __attribute__((address_space(1))) void*)(g), \
    (__attribute__((address_space(3))) void*)(l), 16, 0, 0)

// ---------------------------------------------------------------- embedding + LN1(l=0) fused
__device__ inline float block_sum_256(float v, float* ws) {
    #pragma unroll
    for (int o = 32; o > 0; o >>= 1) v += __shfl_down(v, o);
    const int lane = threadIdx.x & 63, wid = threadIdx.x >> 6;
    if (lane == 0) ws[wid] = v;
    __syncthreads();
    return ws[0] + ws[1] + ws[2] + ws[3];
}

__launch_bounds__(256)
__global__ void gather_ln(const int* __restrict__ ids, const float* __restrict__ emb,
                          float* __restrict__ h, unsigned short* __restrict__ xb,
                          const float* __restrict__ g, const float* __restrict__ bta) {
    __shared__ float ws1[4], ws2[4];
    const int row = blockIdx.x, tid = threadIdx.x;
    const int id = ids[row];
    const int d = tid * 4;
    float4 v = *(const float4*)(emb + (size_t)id * DD + d);
    *(float4*)(h + (size_t)row * DD + d) = v;
    float s = v.x + v.y + v.z + v.w;
    float m = block_sum_256(s, ws1) * (1.0f / 1024.0f);
    float d0 = v.x - m, d1 = v.y - m, d2 = v.z - m, d3 = v.w - m;
    float s2 = d0*d0 + d1*d1 + d2*d2 + d3*d3;
    float rstd = rsqrtf(block_sum_256(s2, ws2) * (1.0f / 1024.0f) + 1e-5f);
    float4 gg = *(const float4*)(g + d);
    float4 bb = *(const float4*)(bta + d);
    ushort4 o;
    o.x = f2b(d0 * rstd * gg.x + bb.x);
    o.y = f2b(d1 * rstd * gg.y + bb.y);
    o.z = f2b(d2 * rstd * gg.z + bb.z);
    o.w = f2b(d3 * rstd * gg.w + bb.w);
    *(ushort4*)(xb + (size_t)row * DD + d) = o;
}

__launch_bounds__(256)
__global__ void logmask_k(const float* __restrict__ am, float* __restrict__ lm) {
    int i = blockIdx.x * 256 + threadIdx.x;
    if (i < BT) lm[i] = logf(fmaxf(am[i], 1e-9f));
}

// ---------------------------------------------------------------- layernorm
__launch_bounds__(256)
__global__ void ln_f32(const float* __restrict__ in, float* __restrict__ out,
                       const float* __restrict__ g, const float* __restrict__ bta) {
    __shared__ float ws1[4], ws2[4];
    const int row = blockIdx.x, tid = threadIdx.x;
    const float* x = in + (size_t)row * DD;
    float4 v = *(const float4*)(x + tid * 4);
    float s = v.x + v.y + v.z + v.w;
    float m = block_sum_256(s, ws1) * (1.0f / 1024.0f);
    float d0 = v.x - m, d1 = v.y - m, d2 = v.z - m, d3 = v.w - m;
    float s2 = d0*d0 + d1*d1 + d2*d2 + d3*d3;
    float rstd = rsqrtf(block_sum_256(s2, ws2) * (1.0f / 1024.0f) + 1e-5f);
    const int d = tid * 4;
    float4 gg = *(const float4*)(g + d);
    float4 bb = *(const float4*)(bta + d);
    float4 o;
    o.x = d0 * rstd * gg.x + bb.x;
    o.y = d1 * rstd * gg.y + bb.y;
    o.z = d2 * rstd * gg.z + bb.z;
    o.w = d3 * rstd * gg.w + bb.w;
    *(float4*)(out + (size_t)row * DD + d) = o;
}

__launch_bounds__(256)
__global__ void ln_bf16(const float* __restrict__ in, unsigned short* __restrict__ out,
                        const float* __restrict__ g, const float* __restrict__ bta) {
    __shared__ float ws1[4], ws2[4];
    const int row = blockIdx.x, tid = threadIdx.x;
    const float* x = in + (size_t)row * DD;
    float4 v = *(const float4*)(x + tid * 4);
    float s = v.x + v.y + v.z + v.w;
    float m = block_sum_256(s, ws1) * (1.0f / 1024.0f);
    float d0 = v.x - m, d1 = v.y - m, d2 = v.z - m, d3 = v.w - m;
    float s2 = d0*d0 + d1*d1 + d2*d2 + d3*d3;
    float rstd = rsqrtf(block_sum_256(s2, ws2) * (1.0f / 1024.0f) + 1e-5f);
    const int d = tid * 4;
    float4 gg = *(const float4*)(g + d);
    float4 bb = *(const float4*)(bta + d);
    ushort4 o;
    o.x = f2b(d0 * rstd * gg.x + bb.x);
    o.y = f2b(d1 * rstd * gg.y + bb.y);
    o.z = f2b(d2 * rstd * gg.z + bb.z);
    o.w = f2b(d3 * rstd * gg.w + bb.w);
    *(ushort4*)(out + (size_t)row * DD + d) = o;
}

// fused: y = LN(in, g2,b2) -> fp32 outf ; LN(y, g1,b1) -> bf16 outb
__launch_bounds__(256)
__global__ void ln_dual(const float* __restrict__ in, float* __restrict__ outf,
                        const float* __restrict__ g2, const float* __restrict__ b2v,
                        unsigned short* __restrict__ outb,
                        const float* __restrict__ g1, const float* __restrict__ b1v) {
    __shared__ float ws1[4], ws2[4], ws3[4], ws4[4];
    const int row = blockIdx.x, tid = threadIdx.x;
    const int d = tid * 4;
    float4 v = *(const float4*)(in + (size_t)row * DD + d);
    float s = v.x + v.y + v.z + v.w;
    float m = block_sum_256(s, ws1) * (1.0f / 1024.0f);
    float d0 = v.x - m, d1 = v.y - m, d2 = v.z - m, d3 = v.w - m;
    float s2 = d0*d0 + d1*d1 + d2*d2 + d3*d3;
    float rstd = rsqrtf(block_sum_256(s2, ws2) * (1.0f / 1024.0f) + 1e-5f);
    float4 gg = *(const float4*)(g2 + d);
    float4 bb = *(const float4*)(b2v + d);
    float4 y;
    y.x = d0 * rstd * gg.x + bb.x;
    y.y = d1 * rstd * gg.y + bb.y;
    y.z = d2 * rstd * gg.z + bb.z;
    y.w = d3 * rstd * gg.w + bb.w;
    *(float4*)(outf + (size_t)row * DD + d) = y;
    float t = y.x + y.y + y.z + y.w;
    float m2 = block_sum_256(t, ws3) * (1.0f / 1024.0f);
    float e0 = y.x - m2, e1 = y.y - m2, e2 = y.z - m2, e3 = y.w - m2;
    float t2 = e0*e0 + e1*e1 + e2*e2 + e3*e3;
    float rstd2 = rsqrtf(block_sum_256(t2, ws4) * (1.0f / 1024.0f) + 1e-5f);
    float4 g1v = *(const float4*)(g1 + d);
    float4 b1x = *(const float4*)(b1v + d);
    ushort4 o;
    o.x = f2b(e0 * rstd2 * g1v.x + b1x.x);
    o.y = f2b(e1 * rstd2 * g1v.y + b1x.y);
    o.z = f2b(e2 * rstd2 * g1v.z + b1x.z);
    o.w = f2b(e3 * rstd2 * g1v.w + b1x.w);
    *(ushort4*)(outb + (size_t)row * DD + d) = o;
}

// ------------------------------------------- all-layer weight transpose (once)
__launch_bounds__(256)
__global__ void wtrans_all(const float* __restrict__ wq, unsigned short* __restrict__ wqo,
                           const float* __restrict__ wa, unsigned short* __restrict__ wao,
                           const float* __restrict__ w1, unsigned short* __restrict__ w1o,
                           const float* __restrict__ w2, unsigned short* __restrict__ w2o) {
    __shared__ float tile[64][65];
    const int l = blockIdx.x / 3072;
    int id = blockIdx.x % 3072;
    const float* W; unsigned short* Wt; int K, N, tx, ty;
    if (id < 768)       { W = wq + (size_t)l*1024*3072; Wt = wqo + (size_t)l*3072*1024; K = 1024; N = 3072; tx = id % 48; ty = id / 48; }
    else if (id < 1024) { id -= 768;  W = wa + (size_t)l*1024*1024; Wt = wao + (size_t)l*1024*1024; K = 1024; N = 1024; tx = id & 15; ty = id >> 4; }
    else if (id < 2048) { id -= 1024; W = w1 + (size_t)l*1024*4096; Wt = w1o + (size_t)l*4096*1024; K = 1024; N = 4096; tx = id & 63; ty = id >> 6; }
    else                { id -= 2048; W = w2 + (size_t)l*4096*1024; Wt = w2o + (size_t)l*1024*4096; K = 4096; N = 1024; tx = id & 15; ty = id >> 4; }
    const int k0 = ty * 64, n0 = tx * 64;
    const int lrow = threadIdx.x >> 4;
    const int lcol = (threadIdx.x & 15) * 4;
    #pragma unroll
    for (int i = 0; i < 4; ++i) {
        const int r = lrow + i * 16;
        *(float4*)&tile[r][lcol] = *(const float4*)(W + (size_t)(k0 + r) * N + n0 + lcol);
    }
    __syncthreads();
    #pragma unroll
    for (int i = 0; i < 4; ++i) {
        const int n = lrow + i * 16;
        ushort4 o;
        o.x = f2b(tile[lcol + 0][n]);
        o.y = f2b(tile[lcol + 1][n]);
        o.z = f2b(tile[lcol + 2][n]);
        o.w = f2b(tile[lcol + 3][n]);
        *(ushort4*)(Wt + (size_t)(n0 + n) * K + k0 + lcol) = o;
    }
}

// ---------------------------------------------------------------- MFMA GEMM
// 16x16x32 frags, BK=32, double-buffered LDS, counted-vmcnt pipeline (T3+T4):
// issue next-tile loads -> s_waitcnt vmcnt(L) (cur tile landed, next stays in
// flight across the barrier) -> raw s_barrier -> compute -> raw s_barrier.
#define BM 128
#define BK 32

__device__ inline float gelu_f(float v) {
    return 0.5f * v * (1.0f + erff(v * 0.70710678118654752f));
}

template<int EPI, int NFRAG>
__launch_bounds__(256)
__global__ void gemm_mfma(const unsigned short* __restrict__ A,
                          const unsigned short* __restrict__ Bt,
                          const float* __restrict__ bias, void* __restrict__ Cv,
                          int M, int K, int N) {
    constexpr int BN = NFRAG * 32;
    constexpr int BG = NFRAG / 2;            // extra B-staging GLOAD per thread
    __shared__ short As[2][BM * BK];         // chunk (row, b) holds global (row, b^((row>>1)&3))
    __shared__ short Bs[2][BN * BK];

    const int tid = threadIdx.x;
    const int wid = tid >> 6, lane = tid & 63;

    // XCD-aware block swizzle (all grids divisible by 8)
    const int nwg = gridDim.x * gridDim.y;
    int bid = blockIdx.y * gridDim.x + blockIdx.x;
    bid = (bid & 7) * (nwg >> 3) + (bid >> 3);
    const int m0 = (bid / gridDim.x) * BM;
    const int n0 = (bid % gridDim.x) * BN;

    const int wr = wid >> 1, wc = wid & 1;
    const int fr = lane & 15, fq = lane >> 4;

    // staging: thread t covers chunk t (= row t>>2, blk t&3) and chunk t+256 (row +64)
    const int rowS = tid >> 2;               // 0..63
    const int blkS = tid & 3;
    const int swz0 = (rowS >> 1) & 3;
    const unsigned short* aS0 = A  + (size_t)(m0 + rowS)      * K + (blkS ^ swz0) * 8;
    const unsigned short* aS1 = A  + (size_t)(m0 + rowS + 64) * K + (blkS ^ swz0) * 8;
    const unsigned short* bS0 = Bt + (size_t)(n0 + rowS)      * K + (blkS ^ swz0) * 8;
    const unsigned short* bS1 = Bt + (size_t)(n0 + rowS + 64) * K + (blkS ^ swz0) * 8;

    // fragment read offsets
    const int sF = (fr >> 1) & 3;
    int aoff[4], boff[NFRAG];
    #pragma unroll
    for (int m = 0; m < 4; ++m) aoff[m] = (wr * 64 + m * 16 + fr) * BK + ((fq ^ sF) * 8);
    #pragma unroll
    for (int n = 0; n < NFRAG; ++n) boff[n] = (wc * (NFRAG * 16) + n * 16 + fr) * BK + ((fq ^ sF) * 8);

    f32x4 acc[4][NFRAG];
    #pragma unroll
    for (int m = 0; m < 4; ++m)
        #pragma unroll
        for (int n = 0; n < NFRAG; ++n) acc[m][n] = (f32x4){0.f, 0.f, 0.f, 0.f};

    const int T = K / BK;

    // prologue: stage tile 0 into buf 0
    GLOAD16(aS0, &As[0][(wid * 64) * 8]);
    GLOAD16(aS1, &As[0][(256 + wid * 64) * 8]);
    GLOAD16(bS0, &Bs[0][(wid * 64) * 8]);
    if (BG > 1) GLOAD16(bS1, &Bs[0][(256 + wid * 64) * 8]);

    int cur = 0;
    for (int t = 0; t < T; ++t) {
        if (t + 1 < T) {                     // prefetch next tile into buf^1
            const int nb = cur ^ 1;
            const size_t ko = (size_t)(t + 1) * BK;
            GLOAD16(aS0 + ko, &As[nb][(wid * 64) * 8]);
            GLOAD16(aS1 + ko, &As[nb][(256 + wid * 64) * 8]);
            GLOAD16(bS0 + ko, &Bs[nb][(wid * 64) * 8]);
            if (BG > 1) GLOAD16(bS1 + ko, &Bs[nb][(256 + wid * 64) * 8]);
            // wait only for the CURRENT tile's loads; next-tile loads stay in flight
            if constexpr (NFRAG == 4) asm volatile("s_waitcnt vmcnt(4)" ::: "memory");
            else                      asm volatile("s_waitcnt vmcnt(3)" ::: "memory");
        } else {
            asm volatile("s_waitcnt vmcnt(0)" ::: "memory");
        }
        __builtin_amdgcn_s_barrier();        // all waves: buf[cur] fully staged
        __builtin_amdgcn_sched_barrier(0);
        bf16x8 af[4], bfr[NFRAG];
        #pragma unroll
        for (int m = 0; m < 4; ++m) af[m] = *(const bf16x8*)&As[cur][aoff[m]];
        #pragma unroll
        for (int n = 0; n < NFRAG; ++n) bfr[n] = *(const bf16x8*)&Bs[cur][boff[n]];
        #pragma unroll
        for (int m = 0; m < 4; ++m)
            #pragma unroll
            for (int n = 0; n < NFRAG; ++n)
                acc[m][n] = __builtin_amdgcn_mfma_f32_16x16x32_bf16(
                    af[m], bfr[n], acc[m][n], 0, 0, 0);
        __builtin_amdgcn_sched_barrier(0);
        __builtin_amdgcn_s_barrier();        // all waves done reading buf[cur]
        cur ^= 1;
    }

    float bias_v[NFRAG];
    #pragma unroll
    for (int n = 0; n < NFRAG; ++n) bias_v[n] = bias[n0 + wc * (NFRAG * 16) + n * 16 + fr];

    #pragma unroll
    for (int m = 0; m < 4; ++m) {
        #pragma unroll
        for (int n = 0; n < NFRAG; ++n) {
            const int col = n0 + wc * (NFRAG * 16) + n * 16 + fr;
            #pragma unroll
            for (int j = 0; j < 4; ++j) {
                const int row = m0 + wr * 64 + m * 16 + fq * 4 + j;
                float v = acc[m][n][j] + bias_v[n];
                if (EPI == 1) {
                    float* C = (float*)Cv;
                    C[(size_t)row * N + col] += v;
                } else {
                    if (EPI == 2) v = gelu_f(v);
                    unsigned short* C = (unsigned short*)Cv;
                    C[(size_t)row * N + col] = f2b(v);
                }
            }
        }
    }
}

// ---------------------------------------------------------------- MFMA attention
// KVBLK=64, double-buffered K/V/lms, one barrier per tile; T14 async-STAGE split:
// V/lm loads issue at tile top, convert+LDS-write AFTER compute (latency hidden).
// grid: 512 blocks, XCD-clustered (each XCD owns 8 bh's -> K/V L2 reuse)
__launch_bounds__(256)
__global__ void attn_mfma(const unsigned short* __restrict__ qkv,
                          const float* __restrict__ lm,
                          unsigned short* __restrict__ ctx) {
    int bid = blockIdx.x;
    const int ww = (bid & 7) * 64 + (bid >> 3);
    const int bh = ww >> 3, qt = ww & 7;
    const int b = bh >> 4, hh = bh & 15;
    const int tid = threadIdx.x, w = tid >> 6, lane = tid & 63;
    const int lo = lane & 31, hf = lane >> 5;
    const int q_row = qt * 128 + w * 32 + lo;

    __shared__ short Ks[2][64 * 64];   // [key][8 chunks], chunk c holds global c^(key&7)
    __shared__ short Vt[2][64 * 72];   // [d][72] f16 (144B padded rows)
    __shared__ float lms[2][64];

    bf16x8 qf[4];
    {
        const unsigned short* qbase = qkv + (size_t)(b * TT + q_row) * 3072 + hh * 192;
        #pragma unroll
        for (int kk = 0; kk < 4; ++kk)
            qf[kk] = *(const bf16x8*)(qbase + (2 * kk + hf) * 8);
    }

    const int r0 = tid >> 3, cS = tid & 7;
    const unsigned short* kp = qkv + (size_t)(b * TT + r0) * 3072 + hh * 192 + 64
                               + ((cS ^ (r0 & 7)) * 8);
    const int vkey = tid & 31, vc = tid >> 5;
    const unsigned short* vp = qkv + (size_t)(b * TT + vkey) * 3072 + hh * 192 + 128 + vc * 8;
    const float* lmrow = lm + b * TT;

    f32x16 o0, o1;
    #pragma unroll
    for (int j = 0; j < 16; ++j) { o0[j] = 0.f; o1[j] = 0.f; }
    float M = -1e30f, S = 0.f;

    {   // stage tile 0 into buf 0
        GLOAD16(kp, &Ks[0][(w * 64) * 8]);
        GLOAD16(kp + (size_t)32 * 3072, &Ks[0][(256 + w * 64) * 8]);
        bf16x8 v0 = *(const bf16x8*)vp;
        bf16x8 v1 = *(const bf16x8*)(vp + (size_t)32 * 3072);
        if (tid < 64) lms[0][tid] = lmrow[tid];
        #pragma unroll
        for (int i = 0; i < 8; ++i) {
            _Float16 h0 = (_Float16)b2f((unsigned short)v0[i]);
            _Float16 h1 = (_Float16)b2f((unsigned short)v1[i]);
            Vt[0][(vc * 8 + i) * 72 + vkey] = *reinterpret_cast<short*>(&h0);
            Vt[0][(vc * 8 + i) * 72 + 32 + vkey] = *reinterpret_cast<short*>(&h1);
        }
    }

    int cur = 0;
    for (int kt = 0; kt < 16; ++kt) {
        __syncthreads();
        const bool pf = (kt < 15);
        bf16x8 v0, v1;
        float lmv = 0.f;
        if (pf) {   // issue next-tile loads; consume AFTER compute (T14 split)
            const int nb = cur ^ 1;
            const size_t off = (size_t)((kt + 1) * 64) * 3072;
            GLOAD16(kp + off, &Ks[nb][(w * 64) * 8]);
            GLOAD16(kp + off + (size_t)32 * 3072, &Ks[nb][(256 + w * 64) * 8]);
            v0 = *(const bf16x8*)(vp + off);
            v1 = *(const bf16x8*)(vp + off + (size_t)32 * 3072);
            if (tid < 64) lmv = lmrow[(kt + 1) * 64 + tid];
        }

        #pragma unroll
        for (int g = 0; g < 2; ++g) {
            f32x16 s16;
            #pragma unroll
            for (int j = 0; j < 16; ++j) s16[j] = 0.f;
            __builtin_amdgcn_s_setprio(1);
            #pragma unroll
            for (int kk = 0; kk < 4; ++kk) {
                const int c = (2 * kk + hf) ^ (lo & 7);
                bf16x8 kf = *(const bf16x8*)&Ks[cur][((g * 32 + lo) * 8 + c) * 8];
                s16 = __builtin_amdgcn_mfma_f32_32x32x16_bf16(kf, qf[kk], s16, 0, 0, 0);
            }
            __builtin_amdgcn_s_setprio(0);

            float p[16];
            float mx = -1e30f;
            #pragma unroll
            for (int j = 0; j < 16; ++j) {
                const int kidx = g * 32 + (j & 3) + 8 * (j >> 2) + 4 * hf;
                float sv = s16[j] * 0.125f + lms[cur][kidx];
                p[j] = sv;
                mx = fmaxf(mx, sv);
            }
            mx = fmaxf(mx, __shfl_xor(mx, 32));
            if (!__all(mx <= M + 8.0f)) {
                const float Mn = fmaxf(M, mx);
                const float f = __expf(M - Mn);
                S *= f;
                #pragma unroll
                for (int j = 0; j < 16; ++j) { o0[j] *= f; o1[j] *= f; }
                M = Mn;
            }

            unsigned short ph[16];
            float ls = 0.f;
            #pragma unroll
            for (int j = 0; j < 16; ++j) {
                _Float16 hq = (_Float16)__expf(p[j] - M);
                ph[j] = *reinterpret_cast<unsigned short*>(&hq);
                ls += (float)hq;
            }
            ls += __shfl_xor(ls, 32);
            S += ls;

            unsigned ra = (unsigned)ph[0]  | ((unsigned)ph[1]  << 16);
            unsigned rb = (unsigned)ph[2]  | ((unsigned)ph[3]  << 16);
            unsigned rc = (unsigned)ph[4]  | ((unsigned)ph[5]  << 16);
            unsigned rd = (unsigned)ph[6]  | ((unsigned)ph[7]  << 16);
            unsigned re = (unsigned)ph[8]  | ((unsigned)ph[9]  << 16);
            unsigned rf = (unsigned)ph[10] | ((unsigned)ph[11] << 16);
            unsigned rg = (unsigned)ph[12] | ((unsigned)ph[13] << 16);
            unsigned rh = (unsigned)ph[14] | ((unsigned)ph[15] << 16);
            plswap32(ra, rc);
            plswap32(rb, rd);
            plswap32(re, rg);
            plswap32(rf, rh);
            union { unsigned u[4]; f16x8 v; } p1, p2;
            p1.u[0] = ra; p1.u[1] = rb; p1.u[2] = rc; p1.u[3] = rd;   // keys g*32+0..15
            p2.u[0] = re; p2.u[1] = rf; p2.u[2] = rg; p2.u[3] = rh;   // keys g*32+16..31

            f16x8 va0 = *(const f16x8*)&Vt[cur][lo * 72 + g * 32 + hf * 8];
            f16x8 va1 = *(const f16x8*)&Vt[cur][lo * 72 + g * 32 + 16 + hf * 8];
            f16x8 vb0 = *(const f16x8*)&Vt[cur][(32 + lo) * 72 + g * 32 + hf * 8];
            f16x8 vb1 = *(const f16x8*)&Vt[cur][(32 + lo) * 72 + g * 32 + 16 + hf * 8];
            __builtin_amdgcn_s_setprio(1);
            o0 = __builtin_amdgcn_mfma_f32_32x32x16_f16(va0, p1.v, o0, 0, 0, 0);
            o0 = __builtin_amdgcn_mfma_f32_32x32x16_f16(va1, p2.v, o0, 0, 0, 0);
            o1 = __builtin_amdgcn_mfma_f32_32x32x16_f16(vb0, p1.v, o1, 0, 0, 0);
            o1 = __builtin_amdgcn_mfma_f32_32x32x16_f16(vb1, p2.v, o1, 0, 0, 0);
            __builtin_amdgcn_s_setprio(0);
        }

        if (pf) {   // write-late: V convert + lms store after compute
            const int nb = cur ^ 1;
            if (tid < 64) lms[nb][tid] = lmv;
            #pragma unroll
            for (int i = 0; i < 8; ++i) {
                _Float16 h0 = (_Float16)b2f((unsigned short)v0[i]);
                _Float16 h1 = (_Float16)b2f((unsigned short)v1[i]);
                Vt[nb][(vc * 8 + i) * 72 + vkey] = *reinterpret_cast<short*>(&h0);
                Vt[nb][(vc * 8 + i) * 72 + 32 + vkey] = *reinterpret_cast<short*>(&h1);
            }
        }
        cur ^= 1;
    }

    const float inv = 1.f / S;
    unsigned short* obase = ctx + (size_t)(b * TT + q_row) * DD + hh * 64;
    #pragma unroll
    for (int g = 0; g < 4; ++g) {
        const int dbase = 8 * g + 4 * hf;
        ushort4 w0, w1;
        w0.x = f2b(o0[4*g+0] * inv); w0.y = f2b(o0[4*g+1] * inv);
        w0.z = f2b(o0[4*g+2] * inv); w0.w = f2b(o0[4*g+3] * inv);
        w1.x = f2b(o1[4*g+0] * inv); w1.y = f2b(o1[4*g+1] * inv);
        w1.z = f2b(o1[4*g+2] * inv); w1.w = f2b(o1[4*g+3] * inv);
        *(ushort4*)(obase + dbase) = w0;
        *(ushort4*)(obase + 32 + dbase) = w1;
    }
}

// ---------------------------------------------------------------- pool + L2 (2-pass)
__launch_bounds__(256)
__global__ void pool_partial(const float* __restrict__ h, const float* __restrict__ pm,
                             float* __restrict__ part) {
    const int b = blockIdx.x >> 4, c = blockIdx.x & 15;
    const int tid = threadIdx.x;
    const float* hp = h + (size_t)(b * TT + c * 64) * DD + tid * 4;
    const float* pp = pm + b * TT + c * 64;
    float4 acc = {0.f, 0.f, 0.f, 0.f};
    for (int t = 0; t < 64; ++t) {
        const float p = pp[t];
        float4 v = *(const float4*)(hp + (size_t)t * DD);
        acc.x += p * v.x; acc.y += p * v.y; acc.z += p * v.z; acc.w += p * v.w;
    }
    *(float4*)(part + (size_t)blockIdx.x * DD + tid * 4) = acc;
}

__launch_bounds__(1024)
__global__ void pool_final(const float* __restrict__ part, const float* __restrict__ pm,
                           float* __restrict__ out) {
    const int b = blockIdx.x, d = threadIdx.x;
    __shared__ float ws[16];
    float s = pm[b * TT + d];
    #pragma unroll
    for (int o = 32; o > 0; o >>= 1) s += __shfl_down(s, o);
    if ((d & 63) == 0) ws[d >> 6] = s;
    __syncthreads();
    float msum = 0.f;
    #pragma unroll
    for (int i = 0; i < 16; ++i) msum += ws[i];

    float acc = 0.f;
    #pragma unroll
    for (int c = 0; c < 16; ++c)
        acc += part[(size_t)(b * 16 + c) * DD + d];
    const float sent = acc / fmaxf(msum, 1e-6f);

    float qv = sent * sent;
    #pragma unroll
    for (int o = 32; o > 0; o >>= 1) qv += __shfl_down(qv, o);
    __syncthreads();
    if ((d & 63) == 0) ws[d >> 6] = qv;
    __syncthreads();
    float nrm = 0.f;
    #pragma unroll
    for (int i = 0; i < 16; ++i) nrm += ws[i];
    nrm = sqrtf(nrm);
    out[b * DD + d] = sent / fmaxf(nrm, 1e-12f);
}

// ---------------------------------------------------------------- launch
extern "C" void kernel_launch(void* const* d_in, const int* in_sizes, int n_in,
                              void* d_out, int out_size, void* d_ws, size_t ws_size,
                              hipStream_t stream) {
    const int*   ids    = (const int*)  d_in[0];
    const float* amask  = (const float*)d_in[1];
    const float* pmask  = (const float*)d_in[2];
    const float* embed  = (const float*)d_in[3];
    const float* ln1_s  = (const float*)d_in[4];
    const float* ln1_b  = (const float*)d_in[5];
    const float* qkv_w  = (const float*)d_in[6];
    const float* qkv_b  = (const float*)d_in[7];
    const float* attn_w = (const float*)d_in[8];
    const float* attn_b = (const float*)d_in[9];
    const float* ln2_s  = (const float*)d_in[10];
    const float* ln2_b  = (const float*)d_in[11];
    const float* fc1_w  = (const float*)d_in[12];
    const float* fc1_b  = (const float*)d_in[13];
    const float* fc2_w  = (const float*)d_in[14];
    const float* fc2_b  = (const float*)d_in[15];

    char* wp = (char*)d_ws;
    float* h = (float*)wp;                 wp += (size_t)BT * DD * 4;
    unsigned short* qkv_bf = (unsigned short*)wp; wp += (size_t)BT * 3072 * 2;
    unsigned short* act_bf = (unsigned short*)wp; wp += (size_t)BT * 4096 * 2;
    unsigned short* x_bf   = (unsigned short*)wp; wp += (size_t)BT * DD * 2;
    unsigned short* wq_t   = (unsigned short*)wp; wp += (size_t)LL * 3072 * 1024 * 2;
    unsigned short* wa_t   = (unsigned short*)wp; wp += (size_t)LL * 1024 * 1024 * 2;
    unsigned short* w1_t   = (unsigned short*)wp; wp += (size_t)LL * 4096 * 1024 * 2;
    unsigned short* w2_t   = (unsigned short*)wp; wp += (size_t)LL * 1024 * 4096 * 2;
    float* lm = (float*)wp;                wp += (size_t)BT * 4;
    float* part = (float*)wp;              wp += (size_t)64 * DD * 4;

    gather_ln<<<BT, 256, 0, stream>>>(ids, embed, h, x_bf, ln1_s, ln1_b);
    logmask_k<<<16, 256, 0, stream>>>(amask, lm);
    wtrans_all<<<LL * 3072, 256, 0, stream>>>(qkv_w, wq_t, attn_w, wa_t,
                                              fc1_w, w1_t, fc2_w, w2_t);

    for (int l = 0; l < LL; ++l) {
        const size_t lD = (size_t)l * DD;
        const unsigned short* wq = wq_t + (size_t)l * 3072 * 1024;
        const unsigned short* wa = wa_t + (size_t)l * 1024 * 1024;
        const unsigned short* w1 = w1_t + (size_t)l * 4096 * 1024;
        const unsigned short* w2 = w2_t + (size_t)l * 1024 * 4096;

        gemm_mfma<0, 4><<<dim3(3072/128, BT/BM), 256, 0, stream>>>(
            x_bf, wq, qkv_b + (size_t)l * 3072, qkv_bf, BT, 1024, 3072);
        attn_mfma<<<512, 256, 0, stream>>>(qkv_bf, lm, x_bf);
        gemm_mfma<1, 2><<<dim3(1024/64, BT/BM), 256, 0, stream>>>(
            x_bf, wa, attn_b + lD, h, BT, 1024, 1024);
        ln_bf16<<<BT, 256, 0, stream>>>(h, x_bf, ln2_s + lD, ln2_b + lD);
        gemm_mfma<2, 4><<<dim3(4096/128, BT/BM), 256, 0, stream>>>(
            x_bf, w1, fc1_b + (size_t)l * 4096, act_bf, BT, 1024, 4096);
        gemm_mfma<1, 2><<<dim3(1024/64, BT/BM), 256, 0, stream>>>(
            act_bf, w2, fc2_b + lD, h, BT, 4096, 1024);

        if (l < LL - 1) {
            ln_dual<<<BT, 256, 0, stream>>>(h, h, ln2_s + lD, ln2_b + lD,
                                            x_bf, ln1_s + lD + DD, ln1_b + lD + DD);
        } else {
            ln_f32<<<BT, 256, 0, stream>>>(h, h, ln2_s + lD, ln2_b + lD);
        }
    }

    pool_partial<<<64, 256, 0, stream>>>(h, pmask, part);
    pool_final<<<BB, 1024, 0, stream>>>(part, pmask, (float*)d_out);
}

// Round 11
// 1763.072 us; speedup vs baseline: 1.0025x; 1.0025x over previous
//
#include <hip/hip_runtime.h>
#include <hip/hip_bf16.h>
#include <math.h>

// Problem constants
#define VV 50257
#define DD 1024
#define LL 6
#define HH 16
#define BB 4
#define TT 1024
#define HD 64
#define BT (BB*TT)          // 4096 rows

typedef __attribute__((ext_vector_type(8))) short bf16x8;
typedef __attribute__((ext_vector_type(8))) _Float16 f16x8;
typedef __attribute__((ext_vector_type(4))) float f32x4;
typedef __attribute__((ext_vector_type(16))) float f32x16;

__device__ inline float b2f(unsigned short u) {
    unsigned x = ((unsigned)u) << 16;
    return __uint_as_float(x);
}
__device__ inline unsigned short f2b(float f) {
    __hip_bfloat16 h = __float2bfloat16(f);   // RNE
    return *reinterpret_cast<unsigned short*>(&h);
}
__device__ inline void plswap32(unsigned &dst, unsigned &src) {
    // v_permlane32_swap_b32: for i in 0..31: swap(dst[i+32], src[i])
    asm("v_permlane32_swap_b32 %0, %1" : "+v"(dst), "+v"(src));
}

#define GLOAD16(g, l) __builtin_amdgcn_global_load_lds( \
    (const __attribute__((address_space(1))) void*)(g), \
    (__attribute__((address_space(3))) void*)(l), 16, 0, 0)

// ---------------------------------------------------------------- embedding + LN1(l=0) + logmask fused
__device__ inline float block_sum_256(float v, float* ws) {
    #pragma unroll
    for (int o = 32; o > 0; o >>= 1) v += __shfl_down(v, o);
    const int lane = threadIdx.x & 63, wid = threadIdx.x >> 6;
    if (lane == 0) ws[wid] = v;
    __syncthreads();
    return ws[0] + ws[1] + ws[2] + ws[3];
}

__launch_bounds__(256)
__global__ void gather_ln(const int* __restrict__ ids, const float* __restrict__ emb,
                          float* __restrict__ h, unsigned short* __restrict__ xb,
                          const float* __restrict__ g, const float* __restrict__ bta,
                          const float* __restrict__ am, float* __restrict__ lm) {
    __shared__ float ws1[4], ws2[4];
    const int row = blockIdx.x, tid = threadIdx.x;
    const int id = ids[row];
    const int d = tid * 4;
    if (tid == 0) lm[row] = logf(fmaxf(am[row], 1e-9f));
    float4 v = *(const float4*)(emb + (size_t)id * DD + d);
    *(float4*)(h + (size_t)row * DD + d) = v;
    float s = v.x + v.y + v.z + v.w;
    float m = block_sum_256(s, ws1) * (1.0f / 1024.0f);
    float d0 = v.x - m, d1 = v.y - m, d2 = v.z - m, d3 = v.w - m;
    float s2 = d0*d0 + d1*d1 + d2*d2 + d3*d3;
    float rstd = rsqrtf(block_sum_256(s2, ws2) * (1.0f / 1024.0f) + 1e-5f);
    float4 gg = *(const float4*)(g + d);
    float4 bb = *(const float4*)(bta + d);
    ushort4 o;
    o.x = f2b(d0 * rstd * gg.x + bb.x);
    o.y = f2b(d1 * rstd * gg.y + bb.y);
    o.z = f2b(d2 * rstd * gg.z + bb.z);
    o.w = f2b(d3 * rstd * gg.w + bb.w);
    *(ushort4*)(xb + (size_t)row * DD + d) = o;
}

// ---------------------------------------------------------------- layernorm
__launch_bounds__(256)
__global__ void ln_f32(const float* __restrict__ in, float* __restrict__ out,
                       const float* __restrict__ g, const float* __restrict__ bta) {
    __shared__ float ws1[4], ws2[4];
    const int row = blockIdx.x, tid = threadIdx.x;
    const float* x = in + (size_t)row * DD;
    float4 v = *(const float4*)(x + tid * 4);
    float s = v.x + v.y + v.z + v.w;
    float m = block_sum_256(s, ws1) * (1.0f / 1024.0f);
    float d0 = v.x - m, d1 = v.y - m, d2 = v.z - m, d3 = v.w - m;
    float s2 = d0*d0 + d1*d1 + d2*d2 + d3*d3;
    float rstd = rsqrtf(block_sum_256(s2, ws2) * (1.0f / 1024.0f) + 1e-5f);
    const int d = tid * 4;
    float4 gg = *(const float4*)(g + d);
    float4 bb = *(const float4*)(bta + d);
    float4 o;
    o.x = d0 * rstd * gg.x + bb.x;
    o.y = d1 * rstd * gg.y + bb.y;
    o.z = d2 * rstd * gg.z + bb.z;
    o.w = d3 * rstd * gg.w + bb.w;
    *(float4*)(out + (size_t)row * DD + d) = o;
}

__launch_bounds__(256)
__global__ void ln_bf16(const float* __restrict__ in, unsigned short* __restrict__ out,
                        const float* __restrict__ g, const float* __restrict__ bta) {
    __shared__ float ws1[4], ws2[4];
    const int row = blockIdx.x, tid = threadIdx.x;
    const float* x = in + (size_t)row * DD;
    float4 v = *(const float4*)(x + tid * 4);
    float s = v.x + v.y + v.z + v.w;
    float m = block_sum_256(s, ws1) * (1.0f / 1024.0f);
    float d0 = v.x - m, d1 = v.y - m, d2 = v.z - m, d3 = v.w - m;
    float s2 = d0*d0 + d1*d1 + d2*d2 + d3*d3;
    float rstd = rsqrtf(block_sum_256(s2, ws2) * (1.0f / 1024.0f) + 1e-5f);
    const int d = tid * 4;
    float4 gg = *(const float4*)(g + d);
    float4 bb = *(const float4*)(bta + d);
    ushort4 o;
    o.x = f2b(d0 * rstd * gg.x + bb.x);
    o.y = f2b(d1 * rstd * gg.y + bb.y);
    o.z = f2b(d2 * rstd * gg.z + bb.z);
    o.w = f2b(d3 * rstd * gg.w + bb.w);
    *(ushort4*)(out + (size_t)row * DD + d) = o;
}

// fused: y = LN(in, g2,b2) -> fp32 outf ; LN(y, g1,b1) -> bf16 outb
__launch_bounds__(256)
__global__ void ln_dual(const float* __restrict__ in, float* __restrict__ outf,
                        const float* __restrict__ g2, const float* __restrict__ b2v,
                        unsigned short* __restrict__ outb,
                        const float* __restrict__ g1, const float* __restrict__ b1v) {
    __shared__ float ws1[4], ws2[4], ws3[4], ws4[4];
    const int row = blockIdx.x, tid = threadIdx.x;
    const int d = tid * 4;
    float4 v = *(const float4*)(in + (size_t)row * DD + d);
    float s = v.x + v.y + v.z + v.w;
    float m = block_sum_256(s, ws1) * (1.0f / 1024.0f);
    float d0 = v.x - m, d1 = v.y - m, d2 = v.z - m, d3 = v.w - m;
    float s2 = d0*d0 + d1*d1 + d2*d2 + d3*d3;
    float rstd = rsqrtf(block_sum_256(s2, ws2) * (1.0f / 1024.0f) + 1e-5f);
    float4 gg = *(const float4*)(g2 + d);
    float4 bb = *(const float4*)(b2v + d);
    float4 y;
    y.x = d0 * rstd * gg.x + bb.x;
    y.y = d1 * rstd * gg.y + bb.y;
    y.z = d2 * rstd * gg.z + bb.z;
    y.w = d3 * rstd * gg.w + bb.w;
    *(float4*)(outf + (size_t)row * DD + d) = y;
    float t = y.x + y.y + y.z + y.w;
    float m2 = block_sum_256(t, ws3) * (1.0f / 1024.0f);
    float e0 = y.x - m2, e1 = y.y - m2, e2 = y.z - m2, e3 = y.w - m2;
    float t2 = e0*e0 + e1*e1 + e2*e2 + e3*e3;
    float rstd2 = rsqrtf(block_sum_256(t2, ws4) * (1.0f / 1024.0f) + 1e-5f);
    float4 g1v = *(const float4*)(g1 + d);
    float4 b1x = *(const float4*)(b1v + d);
    ushort4 o;
    o.x = f2b(e0 * rstd2 * g1v.x + b1x.x);
    o.y = f2b(e1 * rstd2 * g1v.y + b1x.y);
    o.z = f2b(e2 * rstd2 * g1v.z + b1x.z);
    o.w = f2b(e3 * rstd2 * g1v.w + b1x.w);
    *(ushort4*)(outb + (size_t)row * DD + d) = o;
}

// ------------------------------------------- all-layer weight transpose (once)
// Each block: 64 n-cols x 256 k-rows (4 subtiles of 64x64), register-prefetch
// double-buffered so the next subtile's loads overlap the write phase.
// Per-layer blocks: wq 192 (48n x 4kg), wa 64, w1 256, w2 256 -> 768/layer, 4608 total.
__launch_bounds__(256)
__global__ void wtrans_all(const float* __restrict__ wq, unsigned short* __restrict__ wqo,
                           const float* __restrict__ wa, unsigned short* __restrict__ wao,
                           const float* __restrict__ w1, unsigned short* __restrict__ w1o,
                           const float* __restrict__ w2, unsigned short* __restrict__ w2o) {
    __shared__ float tile[64][65];
    const int l = blockIdx.x / 768;
    int id = blockIdx.x % 768;
    const float* W; unsigned short* Wt; int K, N, tn, tk;
    if (id < 192)      { W = wq + (size_t)l*1024*3072; Wt = wqo + (size_t)l*3072*1024; K = 1024; N = 3072; tn = id % 48; tk = id / 48; }
    else if (id < 256) { id -= 192; W = wa + (size_t)l*1024*1024; Wt = wao + (size_t)l*1024*1024; K = 1024; N = 1024; tn = id & 15; tk = id >> 4; }
    else if (id < 512) { id -= 256; W = w1 + (size_t)l*1024*4096; Wt = w1o + (size_t)l*4096*1024; K = 1024; N = 4096; tn = id & 63; tk = id >> 6; }
    else               { id -= 512; W = w2 + (size_t)l*4096*1024; Wt = w2o + (size_t)l*1024*4096; K = 4096; N = 1024; tn = id & 15; tk = id >> 4; }
    const int n0 = tn * 64;
    const int k0 = tk * 256;
    const int lrow = threadIdx.x >> 4;          // 0..15
    const int lcol = (threadIdx.x & 15) * 4;    // 0..60

    float4 r[4];
    #pragma unroll
    for (int i = 0; i < 4; ++i)
        r[i] = *(const float4*)(W + (size_t)(k0 + lrow + i * 16) * N + n0 + lcol);

    for (int s = 0; s < 4; ++s) {
        __syncthreads();                        // previous write phase done
        #pragma unroll
        for (int i = 0; i < 4; ++i)
            *(float4*)&tile[lrow + i * 16][lcol] = r[i];
        if (s < 3) {                            // prefetch next subtile (lands under write phase)
            const int k1 = k0 + (s + 1) * 64;
            #pragma unroll
            for (int i = 0; i < 4; ++i)
                r[i] = *(const float4*)(W + (size_t)(k1 + lrow + i * 16) * N + n0 + lcol);
        }
        __syncthreads();
        const int kb = k0 + s * 64;
        #pragma unroll
        for (int i = 0; i < 4; ++i) {
            const int n = lrow + i * 16;
            ushort4 o;
            o.x = f2b(tile[lcol + 0][n]);
            o.y = f2b(tile[lcol + 1][n]);
            o.z = f2b(tile[lcol + 2][n]);
            o.w = f2b(tile[lcol + 3][n]);
            *(ushort4*)(Wt + (size_t)(n0 + n) * K + kb + lcol) = o;
        }
    }
}

// ---------------------------------------------------------------- MFMA GEMM
// BM=128 fixed; BN = NFRAG*32 (NFRAG=4 -> 128, NFRAG=2 -> 64 for N=1024 grids)
#define BM 128
#define BK 64

__device__ inline float gelu_f(float v) {
    return 0.5f * v * (1.0f + erff(v * 0.70710678118654752f));
}

template<int EPI, int NFRAG>
__launch_bounds__(256)
__global__ void gemm_mfma(const unsigned short* __restrict__ A,
                          const unsigned short* __restrict__ Bt,
                          const float* __restrict__ bias, void* __restrict__ Cv,
                          int M, int K, int N) {
    constexpr int BN = NFRAG * 32;
    __shared__ short As[BM * BK];   // [row][8 chunks of 8]; chunk c holds global c^(row&7)
    __shared__ short Bs[BN * BK];

    const int tid = threadIdx.x;
    const int wid = tid >> 6, lane = tid & 63;

    // XCD-aware block swizzle (all grids divisible by 8)
    const int nwg = gridDim.x * gridDim.y;
    int bid = blockIdx.y * gridDim.x + blockIdx.x;
    bid = (bid & 7) * (nwg >> 3) + (bid >> 3);
    const int m0 = (bid / gridDim.x) * BM;
    const int n0 = (bid % gridDim.x) * BN;

    const int wr = wid >> 1, wc = wid & 1;
    const int fr = lane & 15, fq = lane >> 4;

    const int rowS = tid >> 3;              // 0..31
    const int cS = tid & 7;
    const int coff = (cS ^ (rowS & 7)) * 8; // pre-swizzled source chunk
    const unsigned short* aS = A  + (size_t)(m0 + rowS) * K + coff;
    const unsigned short* bS = Bt + (size_t)(n0 + rowS) * K + coff;
    const size_t rstride = (size_t)32 * K;

    const int key = fr & 7;
    const int c0 = fq ^ key;
    int aoff[4], boff[NFRAG];
    #pragma unroll
    for (int m = 0; m < 4; ++m) aoff[m] = (wr * 64 + m * 16 + fr) * BK + c0 * 8;
    #pragma unroll
    for (int n = 0; n < NFRAG; ++n) boff[n] = (wc * (NFRAG * 16) + n * 16 + fr) * BK + c0 * 8;

    f32x4 acc[4][NFRAG];
    #pragma unroll
    for (int m = 0; m < 4; ++m)
        #pragma unroll
        for (int n = 0; n < NFRAG; ++n) acc[m][n] = (f32x4){0.f, 0.f, 0.f, 0.f};

    for (int kk = 0; kk < K; kk += BK) {
        __syncthreads();
        #pragma unroll
        for (int r = 0; r < 4; ++r)
            GLOAD16(aS + kk + r * rstride, &As[(wid * 64 + r * 256) * 8]);
        #pragma unroll
        for (int r = 0; r < NFRAG; ++r)
            GLOAD16(bS + kk + r * rstride, &Bs[(wid * 64 + r * 256) * 8]);
        __syncthreads();
        #pragma unroll
        for (int s = 0; s < 2; ++s) {
            bf16x8 af[4], bfr[NFRAG];
            #pragma unroll
            for (int m = 0; m < 4; ++m) af[m] = *(const bf16x8*)&As[aoff[m] ^ (s << 5)];
            #pragma unroll
            for (int n = 0; n < NFRAG; ++n) bfr[n] = *(const bf16x8*)&Bs[boff[n] ^ (s << 5)];
            #pragma unroll
            for (int m = 0; m < 4; ++m)
                #pragma unroll
                for (int n = 0; n < NFRAG; ++n)
                    acc[m][n] = __builtin_amdgcn_mfma_f32_16x16x32_bf16(
                        af[m], bfr[n], acc[m][n], 0, 0, 0);
        }
    }

    float bias_v[NFRAG];
    #pragma unroll
    for (int n = 0; n < NFRAG; ++n) bias_v[n] = bias[n0 + wc * (NFRAG * 16) + n * 16 + fr];

    #pragma unroll
    for (int m = 0; m < 4; ++m) {
        #pragma unroll
        for (int n = 0; n < NFRAG; ++n) {
            const int col = n0 + wc * (NFRAG * 16) + n * 16 + fr;
            #pragma unroll
            for (int j = 0; j < 4; ++j) {
                const int row = m0 + wr * 64 + m * 16 + fq * 4 + j;
                float v = acc[m][n][j] + bias_v[n];
                if (EPI == 1) {
                    float* C = (float*)Cv;
                    C[(size_t)row * N + col] += v;
                } else {
                    if (EPI == 2) v = gelu_f(v);
                    unsigned short* C = (unsigned short*)Cv;
                    C[(size_t)row * N + col] = f2b(v);
                }
            }
        }
    }
}

// ---------------------------------------------------------------- MFMA attention
// KVBLK=64, double-buffered K/V/lms, one barrier per tile.
// grid: 512 blocks, XCD-clustered (each XCD owns 8 bh's -> K/V L2 reuse)
__launch_bounds__(256)
__global__ void attn_mfma(const unsigned short* __restrict__ qkv,
                          const float* __restrict__ lm,
                          unsigned short* __restrict__ ctx) {
    int bid = blockIdx.x;
    const int ww = (bid & 7) * 64 + (bid >> 3);
    const int bh = ww >> 3, qt = ww & 7;
    const int b = bh >> 4, hh = bh & 15;
    const int tid = threadIdx.x, w = tid >> 6, lane = tid & 63;
    const int lo = lane & 31, hf = lane >> 5;
    const int q_row = qt * 128 + w * 32 + lo;

    __shared__ short Ks[2][64 * 64];   // [key][8 chunks], chunk c holds global c^(key&7)
    __shared__ short Vt[2][64 * 72];   // [d][72] f16 (144B padded rows)
    __shared__ float lms[2][64];

    bf16x8 qf[4];
    {
        const unsigned short* qbase = qkv + (size_t)(b * TT + q_row) * 3072 + hh * 192;
        #pragma unroll
        for (int kk = 0; kk < 4; ++kk)
            qf[kk] = *(const bf16x8*)(qbase + (2 * kk + hf) * 8);
    }

    const int r0 = tid >> 3, cS = tid & 7;
    const unsigned short* kp = qkv + (size_t)(b * TT + r0) * 3072 + hh * 192 + 64
                               + ((cS ^ (r0 & 7)) * 8);
    const int vkey = tid & 31, vc = tid >> 5;
    const unsigned short* vp = qkv + (size_t)(b * TT + vkey) * 3072 + hh * 192 + 128 + vc * 8;
    const float* lmrow = lm + b * TT;

    f32x16 o0, o1;
    #pragma unroll
    for (int j = 0; j < 16; ++j) { o0[j] = 0.f; o1[j] = 0.f; }
    float M = -1e30f, S = 0.f;

    // stage tile 0 into buf 0
    {
        GLOAD16(kp, &Ks[0][(w * 64) * 8]);
        GLOAD16(kp + (size_t)32 * 3072, &Ks[0][(256 + w * 64) * 8]);
        bf16x8 v0 = *(const bf16x8*)vp;
        bf16x8 v1 = *(const bf16x8*)(vp + (size_t)32 * 3072);
        if (tid < 64) lms[0][tid] = lmrow[tid];
        #pragma unroll
        for (int i = 0; i < 8; ++i) {
            _Float16 h0 = (_Float16)b2f((unsigned short)v0[i]);
            _Float16 h1 = (_Float16)b2f((unsigned short)v1[i]);
            Vt[0][(vc * 8 + i) * 72 + vkey] = *reinterpret_cast<short*>(&h0);
            Vt[0][(vc * 8 + i) * 72 + 32 + vkey] = *reinterpret_cast<short*>(&h1);
        }
    }

    int cur = 0;
    for (int kt = 0; kt < 16; ++kt) {
        __syncthreads();   // staging of buf[cur] complete (vmcnt+lgkm drained per wave)
        if (kt < 15) {     // issue next tile into buf^1; latency hides under compute
            const int nb = cur ^ 1;
            const size_t off = (size_t)((kt + 1) * 64) * 3072;
            GLOAD16(kp + off, &Ks[nb][(w * 64) * 8]);
            GLOAD16(kp + off + (size_t)32 * 3072, &Ks[nb][(256 + w * 64) * 8]);
            bf16x8 v0 = *(const bf16x8*)(vp + off);
            bf16x8 v1 = *(const bf16x8*)(vp + off + (size_t)32 * 3072);
            if (tid < 64) lms[nb][tid] = lmrow[(kt + 1) * 64 + tid];
            #pragma unroll
            for (int i = 0; i < 8; ++i) {
                _Float16 h0 = (_Float16)b2f((unsigned short)v0[i]);
                _Float16 h1 = (_Float16)b2f((unsigned short)v1[i]);
                Vt[nb][(vc * 8 + i) * 72 + vkey] = *reinterpret_cast<short*>(&h0);
                Vt[nb][(vc * 8 + i) * 72 + 32 + vkey] = *reinterpret_cast<short*>(&h1);
            }
        }

        #pragma unroll
        for (int g = 0; g < 2; ++g) {
            // S^T = K @ Q^T for keys g*32..g*32+31
            f32x16 s16;
            #pragma unroll
            for (int j = 0; j < 16; ++j) s16[j] = 0.f;
            __builtin_amdgcn_s_setprio(1);
            #pragma unroll
            for (int kk = 0; kk < 4; ++kk) {
                const int c = (2 * kk + hf) ^ (lo & 7);
                bf16x8 kf = *(const bf16x8*)&Ks[cur][((g * 32 + lo) * 8 + c) * 8];
                s16 = __builtin_amdgcn_mfma_f32_32x32x16_bf16(kf, qf[kk], s16, 0, 0, 0);
            }
            __builtin_amdgcn_s_setprio(0);

            float p[16];
            float mx = -1e30f;
            #pragma unroll
            for (int j = 0; j < 16; ++j) {
                const int kidx = g * 32 + (j & 3) + 8 * (j >> 2) + 4 * hf;
                float sv = s16[j] * 0.125f + lms[cur][kidx];
                p[j] = sv;
                mx = fmaxf(mx, sv);
            }
            mx = fmaxf(mx, __shfl_xor(mx, 32));
            // T13 defer-max: skip rescale while growth <= 8 (exact; P bounded by e^8)
            if (!__all(mx <= M + 8.0f)) {
                const float Mn = fmaxf(M, mx);
                const float f = __expf(M - Mn);
                S *= f;
                #pragma unroll
                for (int j = 0; j < 16; ++j) { o0[j] *= f; o1[j] *= f; }
                M = Mn;
            }

            unsigned short ph[16];
            float ls = 0.f;
            #pragma unroll
            for (int j = 0; j < 16; ++j) {
                _Float16 hq = (_Float16)__expf(p[j] - M);
                ph[j] = *reinterpret_cast<unsigned short*>(&hq);
                ls += (float)hq;
            }
            ls += __shfl_xor(ls, 32);
            S += ls;

            unsigned ra = (unsigned)ph[0]  | ((unsigned)ph[1]  << 16);
            unsigned rb = (unsigned)ph[2]  | ((unsigned)ph[3]  << 16);
            unsigned rc = (unsigned)ph[4]  | ((unsigned)ph[5]  << 16);
            unsigned rd = (unsigned)ph[6]  | ((unsigned)ph[7]  << 16);
            unsigned re = (unsigned)ph[8]  | ((unsigned)ph[9]  << 16);
            unsigned rf = (unsigned)ph[10] | ((unsigned)ph[11] << 16);
            unsigned rg = (unsigned)ph[12] | ((unsigned)ph[13] << 16);
            unsigned rh = (unsigned)ph[14] | ((unsigned)ph[15] << 16);
            plswap32(ra, rc);
            plswap32(rb, rd);
            plswap32(re, rg);
            plswap32(rf, rh);
            union { unsigned u[4]; f16x8 v; } p1, p2;
            p1.u[0] = ra; p1.u[1] = rb; p1.u[2] = rc; p1.u[3] = rd;   // keys g*32+0..15
            p2.u[0] = re; p2.u[1] = rf; p2.u[2] = rg; p2.u[3] = rh;   // keys g*32+16..31

            f16x8 va0 = *(const f16x8*)&Vt[cur][lo * 72 + g * 32 + hf * 8];
            f16x8 va1 = *(const f16x8*)&Vt[cur][lo * 72 + g * 32 + 16 + hf * 8];
            f16x8 vb0 = *(const f16x8*)&Vt[cur][(32 + lo) * 72 + g * 32 + hf * 8];
            f16x8 vb1 = *(const f16x8*)&Vt[cur][(32 + lo) * 72 + g * 32 + 16 + hf * 8];
            __builtin_amdgcn_s_setprio(1);
            o0 = __builtin_amdgcn_mfma_f32_32x32x16_f16(va0, p1.v, o0, 0, 0, 0);
            o0 = __builtin_amdgcn_mfma_f32_32x32x16_f16(va1, p2.v, o0, 0, 0, 0);
            o1 = __builtin_amdgcn_mfma_f32_32x32x16_f16(vb0, p1.v, o1, 0, 0, 0);
            o1 = __builtin_amdgcn_mfma_f32_32x32x16_f16(vb1, p2.v, o1, 0, 0, 0);
            __builtin_amdgcn_s_setprio(0);
        }
        cur ^= 1;
    }

    const float inv = 1.f / S;
    unsigned short* obase = ctx + (size_t)(b * TT + q_row) * DD + hh * 64;
    #pragma unroll
    for (int g = 0; g < 4; ++g) {
        const int dbase = 8 * g + 4 * hf;
        ushort4 w0, w1;
        w0.x = f2b(o0[4*g+0] * inv); w0.y = f2b(o0[4*g+1] * inv);
        w0.z = f2b(o0[4*g+2] * inv); w0.w = f2b(o0[4*g+3] * inv);
        w1.x = f2b(o1[4*g+0] * inv); w1.y = f2b(o1[4*g+1] * inv);
        w1.z = f2b(o1[4*g+2] * inv); w1.w = f2b(o1[4*g+3] * inv);
        *(ushort4*)(obase + dbase) = w0;
        *(ushort4*)(obase + 32 + dbase) = w1;
    }
}

// ---------------------------------------------------------------- pool + L2 (2-pass)
__launch_bounds__(256)
__global__ void pool_partial(const float* __restrict__ h, const float* __restrict__ pm,
                             float* __restrict__ part) {
    const int b = blockIdx.x >> 4, c = blockIdx.x & 15;
    const int tid = threadIdx.x;
    const float* hp = h + (size_t)(b * TT + c * 64) * DD + tid * 4;
    const float* pp = pm + b * TT + c * 64;
    float4 acc = {0.f, 0.f, 0.f, 0.f};
    for (int t = 0; t < 64; ++t) {
        const float p = pp[t];
        float4 v = *(const float4*)(hp + (size_t)t * DD);
        acc.x += p * v.x; acc.y += p * v.y; acc.z += p * v.z; acc.w += p * v.w;
    }
    *(float4*)(part + (size_t)blockIdx.x * DD + tid * 4) = acc;
}

__launch_bounds__(1024)
__global__ void pool_final(const float* __restrict__ part, const float* __restrict__ pm,
                           float* __restrict__ out) {
    const int b = blockIdx.x, d = threadIdx.x;
    __shared__ float ws[16];
    float s = pm[b * TT + d];
    #pragma unroll
    for (int o = 32; o > 0; o >>= 1) s += __shfl_down(s, o);
    if ((d & 63) == 0) ws[d >> 6] = s;
    __syncthreads();
    float msum = 0.f;
    #pragma unroll
    for (int i = 0; i < 16; ++i) msum += ws[i];

    float acc = 0.f;
    #pragma unroll
    for (int c = 0; c < 16; ++c)
        acc += part[(size_t)(b * 16 + c) * DD + d];
    const float sent = acc / fmaxf(msum, 1e-6f);

    float qv = sent * sent;
    #pragma unroll
    for (int o = 32; o > 0; o >>= 1) qv += __shfl_down(qv, o);
    __syncthreads();
    if ((d & 63) == 0) ws[d >> 6] = qv;
    __syncthreads();
    float nrm = 0.f;
    #pragma unroll
    for (int i = 0; i < 16; ++i) nrm += ws[i];
    nrm = sqrtf(nrm);
    out[b * DD + d] = sent / fmaxf(nrm, 1e-12f);
}

// ---------------------------------------------------------------- launch
extern "C" void kernel_launch(void* const* d_in, const int* in_sizes, int n_in,
                              void* d_out, int out_size, void* d_ws, size_t ws_size,
                              hipStream_t stream) {
    const int*   ids    = (const int*)  d_in[0];
    const float* amask  = (const float*)d_in[1];
    const float* pmask  = (const float*)d_in[2];
    const float* embed  = (const float*)d_in[3];
    const float* ln1_s  = (const float*)d_in[4];
    const float* ln1_b  = (const float*)d_in[5];
    const float* qkv_w  = (const float*)d_in[6];
    const float* qkv_b  = (const float*)d_in[7];
    const float* attn_w = (const float*)d_in[8];
    const float* attn_b = (const float*)d_in[9];
    const float* ln2_s  = (const float*)d_in[10];
    const float* ln2_b  = (const float*)d_in[11];
    const float* fc1_w  = (const float*)d_in[12];
    const float* fc1_b  = (const float*)d_in[13];
    const float* fc2_w  = (const float*)d_in[14];
    const float* fc2_b  = (const float*)d_in[15];

    char* wp = (char*)d_ws;
    float* h = (float*)wp;                 wp += (size_t)BT * DD * 4;
    unsigned short* qkv_bf = (unsigned short*)wp; wp += (size_t)BT * 3072 * 2;
    unsigned short* act_bf = (unsigned short*)wp; wp += (size_t)BT * 4096 * 2;
    unsigned short* x_bf   = (unsigned short*)wp; wp += (size_t)BT * DD * 2;
    unsigned short* wq_t   = (unsigned short*)wp; wp += (size_t)LL * 3072 * 1024 * 2;
    unsigned short* wa_t   = (unsigned short*)wp; wp += (size_t)LL * 1024 * 1024 * 2;
    unsigned short* w1_t   = (unsigned short*)wp; wp += (size_t)LL * 4096 * 1024 * 2;
    unsigned short* w2_t   = (unsigned short*)wp; wp += (size_t)LL * 1024 * 4096 * 2;
    float* lm = (float*)wp;                wp += (size_t)BT * 4;
    float* part = (float*)wp;              wp += (size_t)64 * DD * 4;

    gather_ln<<<BT, 256, 0, stream>>>(ids, embed, h, x_bf, ln1_s, ln1_b, amask, lm);
    wtrans_all<<<LL * 768, 256, 0, stream>>>(qkv_w, wq_t, attn_w, wa_t,
                                             fc1_w, w1_t, fc2_w, w2_t);

    for (int l = 0; l < LL; ++l) {
        const size_t lD = (size_t)l * DD;
        const unsigned short* wq = wq_t + (size_t)l * 3072 * 1024;
        const unsigned short* wa = wa_t + (size_t)l * 1024 * 1024;
        const unsigned short* w1 = w1_t + (size_t)l * 4096 * 1024;
        const unsigned short* w2 = w2_t + (size_t)l * 1024 * 4096;

        gemm_mfma<0, 4><<<dim3(3072/128, BT/BM), 256, 0, stream>>>(
            x_bf, wq, qkv_b + (size_t)l * 3072, qkv_bf, BT, 1024, 3072);
        attn_mfma<<<512, 256, 0, stream>>>(qkv_bf, lm, x_bf);
        gemm_mfma<1, 2><<<dim3(1024/64, BT/BM), 256, 0, stream>>>(
            x_bf, wa, attn_b + lD, h, BT, 1024, 1024);
        ln_bf16<<<BT, 256, 0, stream>>>(h, x_bf, ln2_s + lD, ln2_b + lD);
        gemm_mfma<2, 4><<<dim3(4096/128, BT/BM), 256, 0, stream>>>(
            x_bf, w1, fc1_b + (size_t)l * 4096, act_bf, BT, 1024, 4096);
        gemm_mfma<1, 2><<<dim3(1024/64, BT/BM), 256, 0, stream>>>(
            act_bf, w2, fc2_b + lD, h, BT, 4096, 1024);

        if (l < LL - 1) {
            ln_dual<<<BT, 256, 0, stream>>>(h, h, ln2_s + lD, ln2_b + lD,
                                            x_bf, ln1_s + lD + DD, ln1_b + lD + DD);
        } else {
            ln_f32<<<BT, 256, 0, stream>>>(h, h, ln2_s + lD, ln2_b + lD);
        }
    }

    pool_partial<<<64, 256, 0, stream>>>(h, pmask, part);
    pool_final<<<BB, 1024, 0, stream>>>(part, pmask, (float*)d_out);
}

// Round 12
// 1620.542 us; speedup vs baseline: 1.0907x; 1.0880x over previous
//
#include <hip/hip_runtime.h>
#include <hip/hip_bf16.h>
#include <math.h>

// Problem constants
#define VV 50257
#define DD 1024
#define LL 6
#define HH 16
#define BB 4
#define TT 1024
#define HD 64
#define BT (BB*TT)          // 4096 rows

typedef __attribute__((ext_vector_type(8))) short bf16x8;
typedef __attribute__((ext_vector_type(8))) _Float16 f16x8;
typedef __attribute__((ext_vector_type(4))) float f32x4;
typedef __attribute__((ext_vector_type(16))) float f32x16;

__device__ inline float b2f(unsigned short u) {
    unsigned x = ((unsigned)u) << 16;
    return __uint_as_float(x);
}
__device__ inline unsigned short f2b(float f) {
    __hip_bfloat16 h = __float2bfloat16(f);   // RNE
    return *reinterpret_cast<unsigned short*>(&h);
}
__device__ inline void plswap32(unsigned &dst, unsigned &src) {
    // v_permlane32_swap_b32: for i in 0..31: swap(dst[i+32], src[i])
    asm("v_permlane32_swap_b32 %0, %1" : "+v"(dst), "+v"(src));
}

#define GLOAD16(g, l) __builtin_amdgcn_global_load_lds( \
    (const __attribute__((address_space(1))) void*)(g), \
    (__attribute__((address_space(3))) void*)(l), 16, 0, 0)

// ---------------------------------------------------------------- embedding + LN1(l=0) + logmask fused
__device__ inline float block_sum_256(float v, float* ws) {
    #pragma unroll
    for (int o = 32; o > 0; o >>= 1) v += __shfl_down(v, o);
    const int lane = threadIdx.x & 63, wid = threadIdx.x >> 6;
    if (lane == 0) ws[wid] = v;
    __syncthreads();
    return ws[0] + ws[1] + ws[2] + ws[3];
}

__launch_bounds__(256)
__global__ void gather_ln(const int* __restrict__ ids, const float* __restrict__ emb,
                          float* __restrict__ h, unsigned short* __restrict__ xb,
                          const float* __restrict__ g, const float* __restrict__ bta,
                          const float* __restrict__ am, float* __restrict__ lm) {
    __shared__ float ws1[4], ws2[4];
    const int row = blockIdx.x, tid = threadIdx.x;
    const int id = ids[row];
    const int d = tid * 4;
    if (tid == 0) lm[row] = logf(fmaxf(am[row], 1e-9f));
    float4 v = *(const float4*)(emb + (size_t)id * DD + d);
    *(float4*)(h + (size_t)row * DD + d) = v;
    float s = v.x + v.y + v.z + v.w;
    float m = block_sum_256(s, ws1) * (1.0f / 1024.0f);
    float d0 = v.x - m, d1 = v.y - m, d2 = v.z - m, d3 = v.w - m;
    float s2 = d0*d0 + d1*d1 + d2*d2 + d3*d3;
    float rstd = rsqrtf(block_sum_256(s2, ws2) * (1.0f / 1024.0f) + 1e-5f);
    float4 gg = *(const float4*)(g + d);
    float4 bb = *(const float4*)(bta + d);
    ushort4 o;
    o.x = f2b(d0 * rstd * gg.x + bb.x);
    o.y = f2b(d1 * rstd * gg.y + bb.y);
    o.z = f2b(d2 * rstd * gg.z + bb.z);
    o.w = f2b(d3 * rstd * gg.w + bb.w);
    *(ushort4*)(xb + (size_t)row * DD + d) = o;
}

// ---------------------------------------------------------------- layernorm
__launch_bounds__(256)
__global__ void ln_f32(const float* __restrict__ in, float* __restrict__ out,
                       const float* __restrict__ g, const float* __restrict__ bta) {
    __shared__ float ws1[4], ws2[4];
    const int row = blockIdx.x, tid = threadIdx.x;
    const float* x = in + (size_t)row * DD;
    float4 v = *(const float4*)(x + tid * 4);
    float s = v.x + v.y + v.z + v.w;
    float m = block_sum_256(s, ws1) * (1.0f / 1024.0f);
    float d0 = v.x - m, d1 = v.y - m, d2 = v.z - m, d3 = v.w - m;
    float s2 = d0*d0 + d1*d1 + d2*d2 + d3*d3;
    float rstd = rsqrtf(block_sum_256(s2, ws2) * (1.0f / 1024.0f) + 1e-5f);
    const int d = tid * 4;
    float4 gg = *(const float4*)(g + d);
    float4 bb = *(const float4*)(bta + d);
    float4 o;
    o.x = d0 * rstd * gg.x + bb.x;
    o.y = d1 * rstd * gg.y + bb.y;
    o.z = d2 * rstd * gg.z + bb.z;
    o.w = d3 * rstd * gg.w + bb.w;
    *(float4*)(out + (size_t)row * DD + d) = o;
}

__launch_bounds__(256)
__global__ void ln_bf16(const float* __restrict__ in, unsigned short* __restrict__ out,
                        const float* __restrict__ g, const float* __restrict__ bta) {
    __shared__ float ws1[4], ws2[4];
    const int row = blockIdx.x, tid = threadIdx.x;
    const float* x = in + (size_t)row * DD;
    float4 v = *(const float4*)(x + tid * 4);
    float s = v.x + v.y + v.z + v.w;
    float m = block_sum_256(s, ws1) * (1.0f / 1024.0f);
    float d0 = v.x - m, d1 = v.y - m, d2 = v.z - m, d3 = v.w - m;
    float s2 = d0*d0 + d1*d1 + d2*d2 + d3*d3;
    float rstd = rsqrtf(block_sum_256(s2, ws2) * (1.0f / 1024.0f) + 1e-5f);
    const int d = tid * 4;
    float4 gg = *(const float4*)(g + d);
    float4 bb = *(const float4*)(bta + d);
    ushort4 o;
    o.x = f2b(d0 * rstd * gg.x + bb.x);
    o.y = f2b(d1 * rstd * gg.y + bb.y);
    o.z = f2b(d2 * rstd * gg.z + bb.z);
    o.w = f2b(d3 * rstd * gg.w + bb.w);
    *(ushort4*)(out + (size_t)row * DD + d) = o;
}

// fused: y = LN(in, g2,b2) -> fp32 outf ; LN(y, g1,b1) -> bf16 outb
__launch_bounds__(256)
__global__ void ln_dual(const float* __restrict__ in, float* __restrict__ outf,
                        const float* __restrict__ g2, const float* __restrict__ b2v,
                        unsigned short* __restrict__ outb,
                        const float* __restrict__ g1, const float* __restrict__ b1v) {
    __shared__ float ws1[4], ws2[4], ws3[4], ws4[4];
    const int row = blockIdx.x, tid = threadIdx.x;
    const int d = tid * 4;
    float4 v = *(const float4*)(in + (size_t)row * DD + d);
    float s = v.x + v.y + v.z + v.w;
    float m = block_sum_256(s, ws1) * (1.0f / 1024.0f);
    float d0 = v.x - m, d1 = v.y - m, d2 = v.z - m, d3 = v.w - m;
    float s2 = d0*d0 + d1*d1 + d2*d2 + d3*d3;
    float rstd = rsqrtf(block_sum_256(s2, ws2) * (1.0f / 1024.0f) + 1e-5f);
    float4 gg = *(const float4*)(g2 + d);
    float4 bb = *(const float4*)(b2v + d);
    float4 y;
    y.x = d0 * rstd * gg.x + bb.x;
    y.y = d1 * rstd * gg.y + bb.y;
    y.z = d2 * rstd * gg.z + bb.z;
    y.w = d3 * rstd * gg.w + bb.w;
    *(float4*)(outf + (size_t)row * DD + d) = y;
    float t = y.x + y.y + y.z + y.w;
    float m2 = block_sum_256(t, ws3) * (1.0f / 1024.0f);
    float e0 = y.x - m2, e1 = y.y - m2, e2 = y.z - m2, e3 = y.w - m2;
    float t2 = e0*e0 + e1*e1 + e2*e2 + e3*e3;
    float rstd2 = rsqrtf(block_sum_256(t2, ws4) * (1.0f / 1024.0f) + 1e-5f);
    float4 g1v = *(const float4*)(g1 + d);
    float4 b1x = *(const float4*)(b1v + d);
    ushort4 o;
    o.x = f2b(e0 * rstd2 * g1v.x + b1x.x);
    o.y = f2b(e1 * rstd2 * g1v.y + b1x.y);
    o.z = f2b(e2 * rstd2 * g1v.z + b1x.z);
    o.w = f2b(e3 * rstd2 * g1v.w + b1x.w);
    *(ushort4*)(outb + (size_t)row * DD + d) = o;
}

// ------------------------------------------- per-layer weight transpose (L2-hot for GEMMs)
// W[K][N] fp32 -> Wt[N][K] bf16; grid 3072 blocks covers qkv/attn/fc1/fc2 of ONE layer
__launch_bounds__(256)
__global__ void wtrans4(const float* __restrict__ wq, unsigned short* __restrict__ wqo,
                        const float* __restrict__ wa, unsigned short* __restrict__ wao,
                        const float* __restrict__ w1, unsigned short* __restrict__ w1o,
                        const float* __restrict__ w2, unsigned short* __restrict__ w2o) {
    __shared__ float tile[64][65];
    int id = blockIdx.x;
    const float* W; unsigned short* Wt; int K, N, tx, ty;
    if (id < 768)       { W = wq; Wt = wqo; K = 1024; N = 3072; tx = id % 48; ty = id / 48; }
    else if (id < 1024) { id -= 768;  W = wa; Wt = wao; K = 1024; N = 1024; tx = id & 15; ty = id >> 4; }
    else if (id < 2048) { id -= 1024; W = w1; Wt = w1o; K = 1024; N = 4096; tx = id & 63; ty = id >> 6; }
    else                { id -= 2048; W = w2; Wt = w2o; K = 4096; N = 1024; tx = id & 15; ty = id >> 4; }
    const int k0 = ty * 64, n0 = tx * 64;
    const int lrow = threadIdx.x >> 4;
    const int lcol = (threadIdx.x & 15) * 4;
    #pragma unroll
    for (int i = 0; i < 4; ++i) {
        const int r = lrow + i * 16;
        *(float4*)&tile[r][lcol] = *(const float4*)(W + (size_t)(k0 + r) * N + n0 + lcol);
    }
    __syncthreads();
    #pragma unroll
    for (int i = 0; i < 4; ++i) {
        const int n = lrow + i * 16;
        ushort4 o;
        o.x = f2b(tile[lcol + 0][n]);
        o.y = f2b(tile[lcol + 1][n]);
        o.z = f2b(tile[lcol + 2][n]);
        o.w = f2b(tile[lcol + 3][n]);
        *(ushort4*)(Wt + (size_t)(n0 + n) * K + k0 + lcol) = o;
    }
}

// ---------------------------------------------------------------- MFMA GEMM
// BM=128 fixed; BN = NFRAG*32 (NFRAG=4 -> 128, NFRAG=2 -> 64 for N=1024 grids)
#define BM 128
#define BK 64

__device__ inline float gelu_f(float v) {
    return 0.5f * v * (1.0f + erff(v * 0.70710678118654752f));
}

template<int EPI, int NFRAG>
__launch_bounds__(256)
__global__ void gemm_mfma(const unsigned short* __restrict__ A,
                          const unsigned short* __restrict__ Bt,
                          const float* __restrict__ bias, void* __restrict__ Cv,
                          int M, int K, int N) {
    constexpr int BN = NFRAG * 32;
    __shared__ short As[BM * BK];   // [row][8 chunks of 8]; chunk c holds global c^(row&7)
    __shared__ short Bs[BN * BK];

    const int tid = threadIdx.x;
    const int wid = tid >> 6, lane = tid & 63;

    // XCD-aware block swizzle (all grids divisible by 8)
    const int nwg = gridDim.x * gridDim.y;
    int bid = blockIdx.y * gridDim.x + blockIdx.x;
    bid = (bid & 7) * (nwg >> 3) + (bid >> 3);
    const int m0 = (bid / gridDim.x) * BM;
    const int n0 = (bid % gridDim.x) * BN;

    const int wr = wid >> 1, wc = wid & 1;
    const int fr = lane & 15, fq = lane >> 4;

    const int rowS = tid >> 3;              // 0..31
    const int cS = tid & 7;
    const int coff = (cS ^ (rowS & 7)) * 8; // pre-swizzled source chunk
    const unsigned short* aS = A  + (size_t)(m0 + rowS) * K + coff;
    const unsigned short* bS = Bt + (size_t)(n0 + rowS) * K + coff;
    const size_t rstride = (size_t)32 * K;

    const int key = fr & 7;
    const int c0 = fq ^ key;
    int aoff[4], boff[NFRAG];
    #pragma unroll
    for (int m = 0; m < 4; ++m) aoff[m] = (wr * 64 + m * 16 + fr) * BK + c0 * 8;
    #pragma unroll
    for (int n = 0; n < NFRAG; ++n) boff[n] = (wc * (NFRAG * 16) + n * 16 + fr) * BK + c0 * 8;

    f32x4 acc[4][NFRAG];
    #pragma unroll
    for (int m = 0; m < 4; ++m)
        #pragma unroll
        for (int n = 0; n < NFRAG; ++n) acc[m][n] = (f32x4){0.f, 0.f, 0.f, 0.f};

    for (int kk = 0; kk < K; kk += BK) {
        __syncthreads();
        #pragma unroll
        for (int r = 0; r < 4; ++r)
            GLOAD16(aS + kk + r * rstride, &As[(wid * 64 + r * 256) * 8]);
        #pragma unroll
        for (int r = 0; r < NFRAG; ++r)
            GLOAD16(bS + kk + r * rstride, &Bs[(wid * 64 + r * 256) * 8]);
        __syncthreads();
        #pragma unroll
        for (int s = 0; s < 2; ++s) {
            bf16x8 af[4], bfr[NFRAG];
            #pragma unroll
            for (int m = 0; m < 4; ++m) af[m] = *(const bf16x8*)&As[aoff[m] ^ (s << 5)];
            #pragma unroll
            for (int n = 0; n < NFRAG; ++n) bfr[n] = *(const bf16x8*)&Bs[boff[n] ^ (s << 5)];
            #pragma unroll
            for (int m = 0; m < 4; ++m)
                #pragma unroll
                for (int n = 0; n < NFRAG; ++n)
                    acc[m][n] = __builtin_amdgcn_mfma_f32_16x16x32_bf16(
                        af[m], bfr[n], acc[m][n], 0, 0, 0);
        }
    }

    float bias_v[NFRAG];
    #pragma unroll
    for (int n = 0; n < NFRAG; ++n) bias_v[n] = bias[n0 + wc * (NFRAG * 16) + n * 16 + fr];

    #pragma unroll
    for (int m = 0; m < 4; ++m) {
        #pragma unroll
        for (int n = 0; n < NFRAG; ++n) {
            const int col = n0 + wc * (NFRAG * 16) + n * 16 + fr;
            #pragma unroll
            for (int j = 0; j < 4; ++j) {
                const int row = m0 + wr * 64 + m * 16 + fq * 4 + j;
                float v = acc[m][n][j] + bias_v[n];
                if (EPI == 1) {
                    float* C = (float*)Cv;
                    C[(size_t)row * N + col] += v;
                } else {
                    if (EPI == 2) v = gelu_f(v);
                    unsigned short* C = (unsigned short*)Cv;
                    C[(size_t)row * N + col] = f2b(v);
                }
            }
        }
    }
}

// ---------------------------------------------------------------- MFMA attention
// KVBLK=64, double-buffered K/V/lms, one barrier per tile.
// grid: 512 blocks, XCD-clustered (each XCD owns 8 bh's -> K/V L2 reuse)
__launch_bounds__(256)
__global__ void attn_mfma(const unsigned short* __restrict__ qkv,
                          const float* __restrict__ lm,
                          unsigned short* __restrict__ ctx) {
    int bid = blockIdx.x;
    const int ww = (bid & 7) * 64 + (bid >> 3);
    const int bh = ww >> 3, qt = ww & 7;
    const int b = bh >> 4, hh = bh & 15;
    const int tid = threadIdx.x, w = tid >> 6, lane = tid & 63;
    const int lo = lane & 31, hf = lane >> 5;
    const int q_row = qt * 128 + w * 32 + lo;

    __shared__ short Ks[2][64 * 64];   // [key][8 chunks], chunk c holds global c^(key&7)
    __shared__ short Vt[2][64 * 72];   // [d][72] f16 (144B padded rows)
    __shared__ float lms[2][64];

    bf16x8 qf[4];
    {
        const unsigned short* qbase = qkv + (size_t)(b * TT + q_row) * 3072 + hh * 192;
        #pragma unroll
        for (int kk = 0; kk < 4; ++kk)
            qf[kk] = *(const bf16x8*)(qbase + (2 * kk + hf) * 8);
    }

    const int r0 = tid >> 3, cS = tid & 7;
    const unsigned short* kp = qkv + (size_t)(b * TT + r0) * 3072 + hh * 192 + 64
                               + ((cS ^ (r0 & 7)) * 8);
    const int vkey = tid & 31, vc = tid >> 5;
    const unsigned short* vp = qkv + (size_t)(b * TT + vkey) * 3072 + hh * 192 + 128 + vc * 8;
    const float* lmrow = lm + b * TT;

    f32x16 o0, o1;
    #pragma unroll
    for (int j = 0; j < 16; ++j) { o0[j] = 0.f; o1[j] = 0.f; }
    float M = -1e30f, S = 0.f;

    // stage tile 0 into buf 0
    {
        GLOAD16(kp, &Ks[0][(w * 64) * 8]);
        GLOAD16(kp + (size_t)32 * 3072, &Ks[0][(256 + w * 64) * 8]);
        bf16x8 v0 = *(const bf16x8*)vp;
        bf16x8 v1 = *(const bf16x8*)(vp + (size_t)32 * 3072);
        if (tid < 64) lms[0][tid] = lmrow[tid];
        #pragma unroll
        for (int i = 0; i < 8; ++i) {
            _Float16 h0 = (_Float16)b2f((unsigned short)v0[i]);
            _Float16 h1 = (_Float16)b2f((unsigned short)v1[i]);
            Vt[0][(vc * 8 + i) * 72 + vkey] = *reinterpret_cast<short*>(&h0);
            Vt[0][(vc * 8 + i) * 72 + 32 + vkey] = *reinterpret_cast<short*>(&h1);
        }
    }

    int cur = 0;
    for (int kt = 0; kt < 16; ++kt) {
        __syncthreads();   // staging of buf[cur] complete (vmcnt+lgkm drained per wave)
        if (kt < 15) {     // issue next tile into buf^1; latency hides under compute
            const int nb = cur ^ 1;
            const size_t off = (size_t)((kt + 1) * 64) * 3072;
            GLOAD16(kp + off, &Ks[nb][(w * 64) * 8]);
            GLOAD16(kp + off + (size_t)32 * 3072, &Ks[nb][(256 + w * 64) * 8]);
            bf16x8 v0 = *(const bf16x8*)(vp + off);
            bf16x8 v1 = *(const bf16x8*)(vp + off + (size_t)32 * 3072);
            if (tid < 64) lms[nb][tid] = lmrow[(kt + 1) * 64 + tid];
            #pragma unroll
            for (int i = 0; i < 8; ++i) {
                _Float16 h0 = (_Float16)b2f((unsigned short)v0[i]);
                _Float16 h1 = (_Float16)b2f((unsigned short)v1[i]);
                Vt[nb][(vc * 8 + i) * 72 + vkey] = *reinterpret_cast<short*>(&h0);
                Vt[nb][(vc * 8 + i) * 72 + 32 + vkey] = *reinterpret_cast<short*>(&h1);
            }
        }

        #pragma unroll
        for (int g = 0; g < 2; ++g) {
            // S^T = K @ Q^T for keys g*32..g*32+31
            f32x16 s16;
            #pragma unroll
            for (int j = 0; j < 16; ++j) s16[j] = 0.f;
            __builtin_amdgcn_s_setprio(1);
            #pragma unroll
            for (int kk = 0; kk < 4; ++kk) {
                const int c = (2 * kk + hf) ^ (lo & 7);
                bf16x8 kf = *(const bf16x8*)&Ks[cur][((g * 32 + lo) * 8 + c) * 8];
                s16 = __builtin_amdgcn_mfma_f32_32x32x16_bf16(kf, qf[kk], s16, 0, 0, 0);
            }
            __builtin_amdgcn_s_setprio(0);

            float p[16];
            float mx = -1e30f;
            #pragma unroll
            for (int j = 0; j < 16; ++j) {
                const int kidx = g * 32 + (j & 3) + 8 * (j >> 2) + 4 * hf;
                float sv = s16[j] * 0.125f + lms[cur][kidx];
                p[j] = sv;
                mx = fmaxf(mx, sv);
            }
            mx = fmaxf(mx, __shfl_xor(mx, 32));
            // T13 defer-max: skip rescale while growth <= 8 (exact; P bounded by e^8)
            if (!__all(mx <= M + 8.0f)) {
                const float Mn = fmaxf(M, mx);
                const float f = __expf(M - Mn);
                S *= f;
                #pragma unroll
                for (int j = 0; j < 16; ++j) { o0[j] *= f; o1[j] *= f; }
                M = Mn;
            }

            unsigned short ph[16];
            float ls = 0.f;
            #pragma unroll
            for (int j = 0; j < 16; ++j) {
                _Float16 hq = (_Float16)__expf(p[j] - M);
                ph[j] = *reinterpret_cast<unsigned short*>(&hq);
                ls += (float)hq;
            }
            ls += __shfl_xor(ls, 32);
            S += ls;

            unsigned ra = (unsigned)ph[0]  | ((unsigned)ph[1]  << 16);
            unsigned rb = (unsigned)ph[2]  | ((unsigned)ph[3]  << 16);
            unsigned rc = (unsigned)ph[4]  | ((unsigned)ph[5]  << 16);
            unsigned rd = (unsigned)ph[6]  | ((unsigned)ph[7]  << 16);
            unsigned re = (unsigned)ph[8]  | ((unsigned)ph[9]  << 16);
            unsigned rf = (unsigned)ph[10] | ((unsigned)ph[11] << 16);
            unsigned rg = (unsigned)ph[12] | ((unsigned)ph[13] << 16);
            unsigned rh = (unsigned)ph[14] | ((unsigned)ph[15] << 16);
            plswap32(ra, rc);
            plswap32(rb, rd);
            plswap32(re, rg);
            plswap32(rf, rh);
            union { unsigned u[4]; f16x8 v; } p1, p2;
            p1.u[0] = ra; p1.u[1] = rb; p1.u[2] = rc; p1.u[3] = rd;   // keys g*32+0..15
            p2.u[0] = re; p2.u[1] = rf; p2.u[2] = rg; p2.u[3] = rh;   // keys g*32+16..31

            f16x8 va0 = *(const f16x8*)&Vt[cur][lo * 72 + g * 32 + hf * 8];
            f16x8 va1 = *(const f16x8*)&Vt[cur][lo * 72 + g * 32 + 16 + hf * 8];
            f16x8 vb0 = *(const f16x8*)&Vt[cur][(32 + lo) * 72 + g * 32 + hf * 8];
            f16x8 vb1 = *(const f16x8*)&Vt[cur][(32 + lo) * 72 + g * 32 + 16 + hf * 8];
            __builtin_amdgcn_s_setprio(1);
            o0 = __builtin_amdgcn_mfma_f32_32x32x16_f16(va0, p1.v, o0, 0, 0, 0);
            o0 = __builtin_amdgcn_mfma_f32_32x32x16_f16(va1, p2.v, o0, 0, 0, 0);
            o1 = __builtin_amdgcn_mfma_f32_32x32x16_f16(vb0, p1.v, o1, 0, 0, 0);
            o1 = __builtin_amdgcn_mfma_f32_32x32x16_f16(vb1, p2.v, o1, 0, 0, 0);
            __builtin_amdgcn_s_setprio(0);
        }
        cur ^= 1;
    }

    const float inv = 1.f / S;
    unsigned short* obase = ctx + (size_t)(b * TT + q_row) * DD + hh * 64;
    #pragma unroll
    for (int g = 0; g < 4; ++g) {
        const int dbase = 8 * g + 4 * hf;
        ushort4 w0, w1;
        w0.x = f2b(o0[4*g+0] * inv); w0.y = f2b(o0[4*g+1] * inv);
        w0.z = f2b(o0[4*g+2] * inv); w0.w = f2b(o0[4*g+3] * inv);
        w1.x = f2b(o1[4*g+0] * inv); w1.y = f2b(o1[4*g+1] * inv);
        w1.z = f2b(o1[4*g+2] * inv); w1.w = f2b(o1[4*g+3] * inv);
        *(ushort4*)(obase + dbase) = w0;
        *(ushort4*)(obase + 32 + dbase) = w1;
    }
}

// ---------------------------------------------------------------- pool + L2 (2-pass)
__launch_bounds__(256)
__global__ void pool_partial(const float* __restrict__ h, const float* __restrict__ pm,
                             float* __restrict__ part) {
    const int b = blockIdx.x >> 4, c = blockIdx.x & 15;
    const int tid = threadIdx.x;
    const float* hp = h + (size_t)(b * TT + c * 64) * DD + tid * 4;
    const float* pp = pm + b * TT + c * 64;
    float4 acc = {0.f, 0.f, 0.f, 0.f};
    for (int t = 0; t < 64; ++t) {
        const float p = pp[t];
        float4 v = *(const float4*)(hp + (size_t)t * DD);
        acc.x += p * v.x; acc.y += p * v.y; acc.z += p * v.z; acc.w += p * v.w;
    }
    *(float4*)(part + (size_t)blockIdx.x * DD + tid * 4) = acc;
}

__launch_bounds__(1024)
__global__ void pool_final(const float* __restrict__ part, const float* __restrict__ pm,
                           float* __restrict__ out) {
    const int b = blockIdx.x, d = threadIdx.x;
    __shared__ float ws[16];
    float s = pm[b * TT + d];
    #pragma unroll
    for (int o = 32; o > 0; o >>= 1) s += __shfl_down(s, o);
    if ((d & 63) == 0) ws[d >> 6] = s;
    __syncthreads();
    float msum = 0.f;
    #pragma unroll
    for (int i = 0; i < 16; ++i) msum += ws[i];

    float acc = 0.f;
    #pragma unroll
    for (int c = 0; c < 16; ++c)
        acc += part[(size_t)(b * 16 + c) * DD + d];
    const float sent = acc / fmaxf(msum, 1e-6f);

    float qv = sent * sent;
    #pragma unroll
    for (int o = 32; o > 0; o >>= 1) qv += __shfl_down(qv, o);
    __syncthreads();
    if ((d & 63) == 0) ws[d >> 6] = qv;
    __syncthreads();
    float nrm = 0.f;
    #pragma unroll
    for (int i = 0; i < 16; ++i) nrm += ws[i];
    nrm = sqrtf(nrm);
    out[b * DD + d] = sent / fmaxf(nrm, 1e-12f);
}

// ---------------------------------------------------------------- launch
extern "C" void kernel_launch(void* const* d_in, const int* in_sizes, int n_in,
                              void* d_out, int out_size, void* d_ws, size_t ws_size,
                              hipStream_t stream) {
    const int*   ids    = (const int*)  d_in[0];
    const float* amask  = (const float*)d_in[1];
    const float* pmask  = (const float*)d_in[2];
    const float* embed  = (const float*)d_in[3];
    const float* ln1_s  = (const float*)d_in[4];
    const float* ln1_b  = (const float*)d_in[5];
    const float* qkv_w  = (const float*)d_in[6];
    const float* qkv_b  = (const float*)d_in[7];
    const float* attn_w = (const float*)d_in[8];
    const float* attn_b = (const float*)d_in[9];
    const float* ln2_s  = (const float*)d_in[10];
    const float* ln2_b  = (const float*)d_in[11];
    const float* fc1_w  = (const float*)d_in[12];
    const float* fc1_b  = (const float*)d_in[13];
    const float* fc2_w  = (const float*)d_in[14];
    const float* fc2_b  = (const float*)d_in[15];

    char* wp = (char*)d_ws;
    float* h = (float*)wp;                 wp += (size_t)BT * DD * 4;
    unsigned short* qkv_bf = (unsigned short*)wp; wp += (size_t)BT * 3072 * 2;
    unsigned short* act_bf = (unsigned short*)wp; wp += (size_t)BT * 4096 * 2;
    unsigned short* x_bf   = (unsigned short*)wp; wp += (size_t)BT * DD * 2;
    unsigned short* wq_t   = (unsigned short*)wp; wp += (size_t)3072 * 1024 * 2;
    unsigned short* wa_t   = (unsigned short*)wp; wp += (size_t)1024 * 1024 * 2;
    unsigned short* w1_t   = (unsigned short*)wp; wp += (size_t)4096 * 1024 * 2;
    unsigned short* w2_t   = (unsigned short*)wp; wp += (size_t)1024 * 4096 * 2;
    float* lm = (float*)wp;                wp += (size_t)BT * 4;
    float* part = (float*)wp;              wp += (size_t)64 * DD * 4;

    gather_ln<<<BT, 256, 0, stream>>>(ids, embed, h, x_bf, ln1_s, ln1_b, amask, lm);

    for (int l = 0; l < LL; ++l) {
        const size_t lD = (size_t)l * DD;

        wtrans4<<<3072, 256, 0, stream>>>(
            qkv_w + (size_t)l * 1024 * 3072, wq_t,
            attn_w + (size_t)l * 1024 * 1024, wa_t,
            fc1_w + (size_t)l * 1024 * 4096, w1_t,
            fc2_w + (size_t)l * 4096 * 1024, w2_t);

        gemm_mfma<0, 4><<<dim3(3072/128, BT/BM), 256, 0, stream>>>(
            x_bf, wq_t, qkv_b + (size_t)l * 3072, qkv_bf, BT, 1024, 3072);
        attn_mfma<<<512, 256, 0, stream>>>(qkv_bf, lm, x_bf);
        gemm_mfma<1, 2><<<dim3(1024/64, BT/BM), 256, 0, stream>>>(
            x_bf, wa_t, attn_b + lD, h, BT, 1024, 1024);
        ln_bf16<<<BT, 256, 0, stream>>>(h, x_bf, ln2_s + lD, ln2_b + lD);
        gemm_mfma<2, 4><<<dim3(4096/128, BT/BM), 256, 0, stream>>>(
            x_bf, w1_t, fc1_b + (size_t)l * 4096, act_bf, BT, 1024, 4096);
        gemm_mfma<1, 2><<<dim3(1024/64, BT/BM), 256, 0, stream>>>(
            act_bf, w2_t, fc2_b + lD, h, BT, 4096, 1024);

        if (l < LL - 1) {
            ln_dual<<<BT, 256, 0, stream>>>(h, h, ln2_s + lD, ln2_b + lD,
                                            x_bf, ln1_s + lD + DD, ln1_b + lD + DD);
        } else {
            ln_f32<<<BT, 256, 0, stream>>>(h, h, ln2_s + lD, ln2_b + lD);
        }
    }

    pool_partial<<<64, 256, 0, stream>>>(h, pmask, part);
    pool_final<<<BB, 1024, 0, stream>>>(part, pmask, (float*)d_out);
}